// Round 3
// baseline (7939.334 us; speedup 1.0000x reference)
//
#include <hip/hip_runtime.h>
#include <hip/hip_cooperative_groups.h>

namespace cg = cooperative_groups;

#define T_STEPS 32
#define BATCH   16
#define IN_DIM  64
#define OUT_DIM 64
#define L_MEM   4096
#define W_DIM   64
#define NIN     192   // IN+OUT+W
#define CO      332
#define CPB     32    // chunks (blocks) per batch
#define LB      128   // l-slots per block = threads per block
#define NBLK    512   // BATCH * CPB
#define NTHR    128
#define MSTR    129   // LDS mem stride: bank (w+l)%32 -> 2-way, free
#define N_EXTRA 202
#define EX_PER_BLK 7  // 32*7 >= 202

__device__ __forceinline__ float waveSum(float v) {
#pragma unroll
  for (int off = 32; off > 0; off >>= 1) v += __shfl_xor(v, off, 64);
  return v;
}
__device__ __forceinline__ float sigmoidf(float x) { return 1.f / (1.f + __expf(-x)); }
__device__ __forceinline__ float softplusf(float x) { return x > 15.f ? x : log1pf(__expf(x)); }

// non-redundant controller columns: out[0:64], g_r/gam_r/s_r (129..133),
// g_w/gam_w/s_w (199..203), e (204..267), a (268..331)
__device__ __forceinline__ int extra_col(int i) {
  if (i < 64) return i;
  if (i < 69) return 129 + (i - 64);
  if (i < 74) return 199 + (i - 69);
  return 204 + (i - 74);
}

__global__ void __launch_bounds__(NTHR, 1) ntm_kernel(
    const float* __restrict__ inp, const float* __restrict__ Wc,
    const float* __restrict__ bcv, float* __restrict__ dout,
    float* __restrict__ outbuf, float* __restrict__ Rbuf,
    float* __restrict__ Sbuf, float* __restrict__ praw,
    float* __restrict__ haloER, float* __restrict__ haloEW,
    float* __restrict__ haloWR, float* __restrict__ haloWW)
{
  cg::grid_group grid = cg::this_grid();
  const int blk   = blockIdx.x;
  const int b     = blk >> 5;     // batch
  const int chunk = blk & 31;     // L-chunk
  const int tid   = threadIdx.x;  // == local l in l-oriented phases
  const int wave  = tid >> 6;
  const int lane  = tid & 63;

  __shared__ float mem[W_DIM * MSTR];   // 33 KB: mem[w*MSTR + l], block-private
  __shared__ float xin[NIN];
  __shared__ float kr[W_DIM], kw[W_DIM];
  __shared__ float sc[4];               // invnk_r, beta_r, invnk_w, beta_w
  __shared__ float erRl[LB], erWl[LB];  // softmax numerators
  __shared__ float wpRl[LB], wpWl[LB];  // normalized prev weights
  __shared__ float wbRl[LB], wbWl[LB];  // sharpened, unnormalized
  __shared__ float rp2[NTHR];           // read-vector partials

  const int hbase = b * (CPB * 2) + chunk * 2;   // this block's 2 halo slots

  // ---------------- prologue ----------------
  for (int idx = tid; idx < W_DIM * MSTR; idx += NTHR) mem[idx] = 0.f;
  wpRl[tid] = 0.f; wpWl[tid] = 0.f;
  if (chunk == 0 && tid == 0) { wpRl[0] = 1.f; wpWl[0] = 1.f; }
  if (tid == 0) {
    float left = (chunk == 0) ? 1.f : 0.f;   // w0 one-hot at l==0
    haloWR[hbase + 0] = left; haloWW[hbase + 0] = left;
    haloWR[hbase + 1] = 0.f;  haloWW[hbase + 1] = 0.f;
    haloER[hbase + 0] = 0.f;  haloEW[hbase + 0] = 0.f;
    haloER[hbase + 1] = 0.f;  haloEW[hbase + 1] = 0.f;
  }
  if (chunk == 0) {
    if (tid < W_DIM) Rbuf[b * W_DIM + tid] = 0.f;
    if (tid < OUT_DIM) {
      outbuf[b * OUT_DIM + tid] = 0.f;
      outbuf[(BATCH + b) * OUT_DIM + tid] = 0.f;
    }
    if (tid == 0) {
      Sbuf[b] = 0.f; Sbuf[16 + b] = 0.f; Sbuf[32 + b] = 0.f; Sbuf[48 + b] = 0.f;
    }
  }
  __threadfence();
  grid.sync();

  for (int t = 0; t < T_STEPS; ++t) {
    // ---------------- phase 1: controller columns ----------------
    {
      const float* xb = inp + ((size_t)t * BATCH + b) * IN_DIM;
      const float* ob = outbuf + ((t & 1) * BATCH + b) * OUT_DIM;
      for (int j = tid; j < NIN; j += NTHR) {
        float v;
        if (j < IN_DIM)                v = xb[j];
        else if (j < IN_DIM + OUT_DIM) v = ob[j - IN_DIM];
        else                           v = Rbuf[b * W_DIM + (j - IN_DIM - OUT_DIM)];
        xin[j] = v;
      }
      __syncthreads();

      // colA: redundant k_r / k_w; colB: betas + this block's extras
      const int colA = (tid < 64) ? (64 + tid) : (134 + (tid - 64));
      int colB = -1, eidx = -1;
      if (tid == 0)      colB = 128;            // beta_r
      else if (tid == 1) colB = 198;            // beta_w
      else if (tid < 2 + EX_PER_BLK) {
        int e = chunk * EX_PER_BLK + (tid - 2);
        if (e < N_EXTRA) { eidx = e; colB = extra_col(e); }
      }
      float accA = bcv[colA];
      float accB = (colB >= 0) ? bcv[colB] : 0.f;
      const float* wcA = Wc + colA;
      const float* wcB = Wc + (colB >= 0 ? colB : 0);
#pragma unroll 8
      for (int i = 0; i < NIN; ++i) {
        float x = xin[i];
        accA = fmaf(x, wcA[(size_t)i * CO], accA);
        accB = fmaf(x, wcB[(size_t)i * CO], accB);
      }
      if (tid < 64) kr[tid] = accA; else kw[tid - 64] = accA;
      if (tid == 0)      sc[1] = softplusf(accB);
      else if (tid == 1) sc[3] = softplusf(accB);
      else if (eidx >= 0) {
        praw[b * CO + colB] = accB;
        if (colB < OUT_DIM) {
          dout[((size_t)t * BATCH + b) * OUT_DIM + colB] = accB;
          outbuf[(((t + 1) & 1) * BATCH + b) * OUT_DIM + colB] = accB;
        }
      }
      __syncthreads();
      if (wave == 0) {
        float v = kr[lane];
        float ss = waveSum(v * v);
        if (lane == 0) sc[0] = 1.f / sqrtf(ss + 1e-14f);
      } else {
        float v = kw[lane];
        float ss = waveSum(v * v);
        if (lane == 0) sc[2] = 1.f / sqrtf(ss + 1e-14f);
      }
      __syncthreads();
    }

    // ---------------- phase 2: content addressing (thread per l) ----------------
    {
      const float invnkR = sc[0], betaR = sc[1], invnkW = sc[2], betaW = sc[3];
      float ss = 0.f, dr = 0.f, dw = 0.f;
#pragma unroll 8
      for (int w = 0; w < W_DIM; ++w) {
        float v = mem[w * MSTR + tid];
        ss = fmaf(v, v, ss);
        dr = fmaf(v, kr[w], dr);
        dw = fmaf(v, kw[w], dw);
      }
      float rinv = rsqrtf(ss + 1e-14f);
      float Kr = dr * rinv * invnkR;
      float Kw = dw * rinv * invnkW;
      // exp(beta*(K-1)): K<=1 -> always stable; batch-constant shift cancels
      float eRv = __expf(betaR * (Kr - 1.f));
      float eWv = __expf(betaW * (Kw - 1.f));
      erRl[tid] = eRv; erWl[tid] = eWv;
      if (tid == 0)      { haloER[hbase + 0] = eRv; haloEW[hbase + 0] = eWv; }
      if (tid == LB - 1) { haloER[hbase + 1] = eRv; haloEW[hbase + 1] = eWv; }
      float s1 = waveSum(eRv);
      float s2 = waveSum(eWv);
      if (lane == 0) { atomicAdd(&Sbuf[b], s1); atomicAdd(&Sbuf[16 + b], s2); }
      if (chunk == 0 && tid == 0) { Sbuf[32 + b] = 0.f; Sbuf[48 + b] = 0.f; }  // zero P
    }
    __threadfence();
    grid.sync();   // sync a

    // ---------------- phase 3: gate + shift + sharpen (thread per l) ----------------
    {
      const float invSR = 1.f / Sbuf[b], invSW = 1.f / Sbuf[16 + b];
      const float* pb = praw + b * CO;
      float gR  = sigmoidf(pb[129]);
      float gaR = softplusf(pb[130]) + 1.f;
      float x0 = pb[131], x1 = pb[132], x2 = pb[133];
      float mx = fmaxf(x0, fmaxf(x1, x2));
      float e0 = __expf(x0 - mx), e1 = __expf(x1 - mx), e2 = __expf(x2 - mx);
      float es = 1.f / (e0 + e1 + e2);
      float sr0 = e0 * es, sr1 = e1 * es, sr2 = e2 * es;
      float gW  = sigmoidf(pb[199]);
      float gaW = softplusf(pb[200]) + 1.f;
      float y0 = pb[201], y1 = pb[202], y2 = pb[203];
      float my = fmaxf(y0, fmaxf(y1, y2));
      float f0 = __expf(y0 - my), f1 = __expf(y1 - my), f2 = __expf(y2 - my);
      float fs = 1.f / (f0 + f1 + f2);
      float sw0 = f0 * fs, sw1 = f1 * fs, sw2 = f2 * fs;

      const int hl = b * (CPB * 2) + ((chunk + CPB - 1) & (CPB - 1)) * 2 + 1;
      const int hr = b * (CPB * 2) + ((chunk + 1) & (CPB - 1)) * 2 + 0;
      float erm = (tid == 0)      ? haloER[hl] : erRl[tid - 1];
      float erp = (tid == LB - 1) ? haloER[hr] : erRl[tid + 1];
      float ewm = (tid == 0)      ? haloEW[hl] : erWl[tid - 1];
      float ewp = (tid == LB - 1) ? haloEW[hr] : erWl[tid + 1];
      float prm = (tid == 0)      ? haloWR[hl] : wpRl[tid - 1];
      float prp = (tid == LB - 1) ? haloWR[hr] : wpRl[tid + 1];
      float pwm = (tid == 0)      ? haloWW[hl] : wpWl[tid - 1];
      float pwp = (tid == LB - 1) ? haloWW[hr] : wpWl[tid + 1];

      float aR = gR * invSR, bRc = 1.f - gR;
      float wgm = aR * erm       + bRc * prm;
      float wg0 = aR * erRl[tid] + bRc * wpRl[tid];
      float wgp = aR * erp       + bRc * prp;
      float wR = __powf(sr0 * wgm + sr1 * wg0 + sr2 * wgp, gaR);
      wbRl[tid] = wR;
      float aW = gW * invSW, bWc = 1.f - gW;
      float vgm = aW * ewm       + bWc * pwm;
      float vg0 = aW * erWl[tid] + bWc * wpWl[tid];
      float vgp = aW * ewp       + bWc * pwp;
      float wW = __powf(sw0 * vgm + sw1 * vg0 + sw2 * vgp, gaW);
      wbWl[tid] = wW;
      float p1 = waveSum(wR), p2 = waveSum(wW);
      if (lane == 0) { atomicAdd(&Sbuf[32 + b], p1); atomicAdd(&Sbuf[48 + b], p2); }
      if (chunk == 0 && tid < W_DIM) Rbuf[b * W_DIM + tid] = 0.f;   // zero R
    }
    __threadfence();
    grid.sync();   // sync b

    // ---------------- phase 4: read vector + memory update ----------------
    {
      const float invPR = 1.f / Sbuf[32 + b];
      const float invPW = 1.f / Sbuf[48 + b];
      // l-oriented: finalize weights, publish halos
      float rwl = wbRl[tid] * invPR;
      float wwl = wbWl[tid] * invPW;
      wpRl[tid] = rwl;            // w_prev for next step
      wpWl[tid] = wwl;
      if (tid == 0)      { haloWR[hbase + 0] = rwl; haloWW[hbase + 0] = wwl; }
      if (tid == LB - 1) { haloWR[hbase + 1] = rwl; haloWW[hbase + 1] = wwl; }
      __syncthreads();
      // w-oriented: thread (w = tid&63, g = tid>>6) handles l in [g*64, g*64+64)
      const int w = tid & 63, g = tid >> 6;
      const float e_w = sigmoidf(praw[b * CO + 204 + w]);
      const float a_w = praw[b * CO + 268 + w];
      float racc = 0.f;
      const int lb0 = g * 64;
#pragma unroll 8
      for (int i = 0; i < 64; ++i) {
        const int l = lb0 + i;
        float v   = mem[w * MSTR + l];
        float rwv = wpRl[l];        // broadcast
        float wwv = wpWl[l];        // broadcast
        racc = fmaf(v, rwv, racc);
        float nv = fmaf(v, -(wwv * e_w), v);   // v*(1 - ww*e)
        mem[w * MSTR + l] = fmaf(wwv, a_w, nv); // + ww*a
      }
      rp2[tid] = racc;
      __syncthreads();
      if (tid < W_DIM) atomicAdd(&Rbuf[b * W_DIM + tid], rp2[tid] + rp2[64 + tid]);
      if (chunk == 0 && tid == 0) { Sbuf[b] = 0.f; Sbuf[16 + b] = 0.f; }  // zero S
    }
    __threadfence();
    grid.sync();   // sync c
  }
}

extern "C" void kernel_launch(void* const* d_in, const int* in_sizes, int n_in,
                              void* d_out, int out_size, void* d_ws, size_t ws_size,
                              hipStream_t stream) {
  const float* inp = (const float*)d_in[0];
  const float* Wc  = (const float*)d_in[1];
  const float* bcv = (const float*)d_in[2];
  float* dout = (float*)d_out;
  float* ws = (float*)d_ws;

  size_t off = 0;
  float* outbuf = ws + off; off += 2 * BATCH * OUT_DIM;
  float* Rbuf   = ws + off; off += BATCH * W_DIM;
  float* Sbuf   = ws + off; off += 64;
  float* praw   = ws + off; off += BATCH * CO;
  float* haloER = ws + off; off += BATCH * CPB * 2;
  float* haloEW = ws + off; off += BATCH * CPB * 2;
  float* haloWR = ws + off; off += BATCH * CPB * 2;
  float* haloWW = ws + off; off += BATCH * CPB * 2;

  void* args[] = { (void*)&inp, (void*)&Wc, (void*)&bcv, (void*)&dout,
                   (void*)&outbuf, (void*)&Rbuf, (void*)&Sbuf, (void*)&praw,
                   (void*)&haloER, (void*)&haloEW, (void*)&haloWR, (void*)&haloWW };
  hipLaunchCooperativeKernel((void*)ntm_kernel, dim3(NBLK), dim3(NTHR),
                             args, 0, stream);
}

// Round 4
// 1492.949 us; speedup vs baseline: 5.3179x; 5.3179x over previous
//
#include <hip/hip_runtime.h>

#define T_STEPS 32
#define BATCH   16
#define L_MEM   4096
#define W_DIM   64
#define NIN     192   // IN + OUT + W
#define CO      332
#define NTHR    1024
#define NWAVE   16

__device__ __forceinline__ float waveSum(float v) {
#pragma unroll
  for (int off = 32; off > 0; off >>= 1) v += __shfl_xor(v, off, 64);
  return v;
}
__device__ __forceinline__ float sigmoidf(float x) { return 1.f / (1.f + __expf(-x)); }
__device__ __forceinline__ float softplusf(float x) { return x > 15.f ? x : log1pf(__expf(x)); }

// One block per batch element. mem[b][w][l] w-major in global (block-private,
// L2-resident). Thread tid owns l in [4*tid, 4*tid+4). No cross-block
// communication of any kind -> no device fences, no grid sync, plain launch.
__global__ void __launch_bounds__(NTHR, 4) ntm_kernel(
    const float* __restrict__ inp, const float* __restrict__ Wc,
    const float* __restrict__ bcv, float* __restrict__ dout,
    float* __restrict__ memG)
{
  const int b    = blockIdx.x;
  const int tid  = threadIdx.x;
  const int wv   = tid >> 6;
  const int lane = tid & 63;

  __shared__ float xin[NIN];
  __shared__ float kr[64], kw[64];
  __shared__ float psc[12];          // bR,gR,gaR,sR0..2, bW,gW,gaW,sW0..2 (raw)
  __shared__ float elds[64], alds[64];
  __shared__ float outb[2][64];      // out ping-pong
  __shared__ float rsum[64];         // read vector (normalized)
  __shared__ float rwl[L_MEM], wwl[L_MEM];   // normalized weights for update sweep
  __shared__ float scrA[16], scrB[16];
  __shared__ float red[4];           // invSR, invSW, invPR, invPW
  __shared__ float sc2[2];           // invnkR, invnkW
  __shared__ float eRj3[16], eRj0[16], eWj3[16], eWj0[16];  // er wave-edges
  __shared__ float pRj3[16], pRj0[16], pWj3[16], pWj0[16];  // wp wave-edges

  float4* mem4 = (float4*)(memG + (size_t)b * W_DIM * L_MEM);

  // ---------------- prologue ----------------
  for (int i4 = tid; i4 < W_DIM * L_MEM / 4; i4 += NTHR)
    mem4[i4] = make_float4(0.f, 0.f, 0.f, 0.f);
  if (tid < 64) { rsum[tid] = 0.f; outb[0][tid] = 0.f; outb[1][tid] = 0.f; }
  float wpR[4] = {0.f, 0.f, 0.f, 0.f}, wpW[4] = {0.f, 0.f, 0.f, 0.f};
  if (tid == 0) { wpR[0] = 1.f; wpW[0] = 1.f; }   // w0 one-hot at l=0
  if (lane == 63) { pRj3[wv] = 0.f; pWj3[wv] = 0.f; }
  if (lane == 0)  { float v0 = (tid == 0) ? 1.f : 0.f; pRj0[wv] = v0; pWj0[wv] = v0; }
  __syncthreads();

  for (int t = 0; t < T_STEPS; ++t) {
    // ---------------- stage controller input ----------------
    if (tid < 64)       xin[tid] = inp[((size_t)t * BATCH + b) * 64 + tid];
    else if (tid < 128) xin[tid] = outb[(t + 1) & 1][tid - 64];
    else if (tid < 192) xin[tid] = rsum[tid - 128];
    __syncthreads();

    // ---------------- controller GEMM: one column per thread ----------------
    if (tid < CO) {
      float acc = bcv[tid];
      const float* wcp = Wc + tid;
#pragma unroll 8
      for (int i = 0; i < NIN; ++i) acc = fmaf(xin[i], wcp[i * CO], acc);
      if (tid < 64) {
        outb[t & 1][tid] = acc;
        dout[((size_t)t * BATCH + b) * 64 + tid] = acc;
      }
      else if (tid < 128)  kr[tid - 64] = acc;
      else if (tid < 134)  psc[tid - 128] = acc;          // beta_r,g_r,ga_r,s_r0..2
      else if (tid < 198)  kw[tid - 134] = acc;
      else if (tid < 204)  psc[6 + (tid - 198)] = acc;    // beta_w,g_w,ga_w,s_w0..2
      else if (tid < 268)  elds[tid - 204] = sigmoidf(acc);
      else                 alds[tid - 268] = acc;
    }
    __syncthreads();
    if (wv == 0) {
      float v = kr[lane]; float s2 = waveSum(v * v);
      if (lane == 0) sc2[0] = 1.f / sqrtf(s2 + 1e-14f);
    } else if (wv == 1) {
      float v = kw[lane]; float s2 = waveSum(v * v);
      if (lane == 0) sc2[1] = 1.f / sqrtf(s2 + 1e-14f);
    }
    __syncthreads();

    // ---------------- sweep A: cosine sims -> er (thread per 4 consecutive l) ----------------
    float erR[4], erW[4];
    {
      const float betaR = softplusf(psc[0]), betaW = softplusf(psc[6]);
      const float invnkR = sc2[0], invnkW = sc2[1];
      float ss[4] = {0,0,0,0}, dr[4] = {0,0,0,0}, dw[4] = {0,0,0,0};
#pragma unroll 4
      for (int w = 0; w < 64; ++w) {
        float4 v = mem4[w * 1024 + tid];
        float krw = kr[w], kww = kw[w];
        ss[0] = fmaf(v.x, v.x, ss[0]); ss[1] = fmaf(v.y, v.y, ss[1]);
        ss[2] = fmaf(v.z, v.z, ss[2]); ss[3] = fmaf(v.w, v.w, ss[3]);
        dr[0] = fmaf(v.x, krw, dr[0]); dr[1] = fmaf(v.y, krw, dr[1]);
        dr[2] = fmaf(v.z, krw, dr[2]); dr[3] = fmaf(v.w, krw, dr[3]);
        dw[0] = fmaf(v.x, kww, dw[0]); dw[1] = fmaf(v.y, kww, dw[1]);
        dw[2] = fmaf(v.z, kww, dw[2]); dw[3] = fmaf(v.w, kww, dw[3]);
      }
      float sRloc = 0.f, sWloc = 0.f;
#pragma unroll
      for (int j = 0; j < 4; ++j) {
        float rinv = rsqrtf(ss[j] + 1e-14f);
        float Kr = dr[j] * rinv * invnkR;
        float Kw = dw[j] * rinv * invnkW;
        erR[j] = __expf(betaR * (Kr - 1.f));   // stable: K<=1
        erW[j] = __expf(betaW * (Kw - 1.f));
        sRloc += erR[j]; sWloc += erW[j];
      }
      if (lane == 63) { eRj3[wv] = erR[3]; eWj3[wv] = erW[3]; }
      if (lane == 0)  { eRj0[wv] = erR[0]; eWj0[wv] = erW[0]; }
      sRloc = waveSum(sRloc); sWloc = waveSum(sWloc);
      if (lane == 0) { scrA[wv] = sRloc; scrB[wv] = sWloc; }
    }
    __syncthreads();
    if (wv == 0) { float v = (lane < 16) ? scrA[lane] : 0.f; v = waveSum(v); if (lane == 0) red[0] = 1.f / v; }
    if (wv == 1) { float v = (lane < 16) ? scrB[lane] : 0.f; v = waveSum(v); if (lane == 0) red[1] = 1.f / v; }
    __syncthreads();

    // ---------------- gate + shift + sharpen (registers + shuffles) ----------------
    {
      const float invSR = red[0], invSW = red[1];
      float gR = sigmoidf(psc[1]), gaR = softplusf(psc[2]) + 1.f;
      float x0 = psc[3], x1 = psc[4], x2 = psc[5];
      float mx = fmaxf(x0, fmaxf(x1, x2));
      float e0 = __expf(x0 - mx), e1 = __expf(x1 - mx), e2 = __expf(x2 - mx);
      float es = 1.f / (e0 + e1 + e2);
      float sr0 = e0 * es, sr1 = e1 * es, sr2 = e2 * es;
      float gW = sigmoidf(psc[7]), gaW = softplusf(psc[8]) + 1.f;
      float y0 = psc[9], y1 = psc[10], y2 = psc[11];
      float my = fmaxf(y0, fmaxf(y1, y2));
      float f0 = __expf(y0 - my), f1 = __expf(y1 - my), f2 = __expf(y2 - my);
      float fs = 1.f / (f0 + f1 + f2);
      float sw0 = f0 * fs, sw1 = f1 * fs, sw2 = f2 * fs;
      const float aR = gR * invSR, bR = 1.f - gR;
      const float aW = gW * invSW, bW = 1.f - gW;

      // +/-1 neighbors (circular over L): shuffle within wave, LDS at wave edges
      float eRm = __shfl_up(erR[3], 1, 64);   if (lane == 0)  eRm = eRj3[(wv + 15) & 15];
      float eRp = __shfl_down(erR[0], 1, 64); if (lane == 63) eRp = eRj0[(wv + 1) & 15];
      float eWm = __shfl_up(erW[3], 1, 64);   if (lane == 0)  eWm = eWj3[(wv + 15) & 15];
      float eWp = __shfl_down(erW[0], 1, 64); if (lane == 63) eWp = eWj0[(wv + 1) & 15];
      float pRm = __shfl_up(wpR[3], 1, 64);   if (lane == 0)  pRm = pRj3[(wv + 15) & 15];
      float pRp = __shfl_down(wpR[0], 1, 64); if (lane == 63) pRp = pRj0[(wv + 1) & 15];
      float pWm = __shfl_up(wpW[3], 1, 64);   if (lane == 0)  pWm = pWj3[(wv + 15) & 15];
      float pWp = __shfl_down(wpW[0], 1, 64); if (lane == 63) pWp = pWj0[(wv + 1) & 15];

      float wgR[6], wgW[6];
      wgR[0] = aR * eRm + bR * pRm;  wgW[0] = aW * eWm + bW * pWm;
#pragma unroll
      for (int j = 0; j < 4; ++j) {
        wgR[j + 1] = aR * erR[j] + bR * wpR[j];
        wgW[j + 1] = aW * erW[j] + bW * wpW[j];
      }
      wgR[5] = aR * eRp + bR * pRp;  wgW[5] = aW * eWp + bW * pWp;

      float wbR[4], wbW[4], pRs = 0.f, pWs = 0.f;
#pragma unroll
      for (int j = 0; j < 4; ++j) {
        wbR[j] = __powf(sr0 * wgR[j] + sr1 * wgR[j + 1] + sr2 * wgR[j + 2], gaR);
        wbW[j] = __powf(sw0 * wgW[j] + sw1 * wgW[j + 1] + sw2 * wgW[j + 2], gaW);
        pRs += wbR[j]; pWs += wbW[j];
      }
      pRs = waveSum(pRs); pWs = waveSum(pWs);
      if (lane == 0) { scrA[wv] = pRs; scrB[wv] = pWs; }
      __syncthreads();
      if (wv == 0) { float v = (lane < 16) ? scrA[lane] : 0.f; v = waveSum(v); if (lane == 0) red[2] = 1.f / v; }
      if (wv == 1) { float v = (lane < 16) ? scrB[lane] : 0.f; v = waveSum(v); if (lane == 0) red[3] = 1.f / v; }
      __syncthreads();
      const float invPR = red[2], invPW = red[3];
#pragma unroll
      for (int j = 0; j < 4; ++j) {
        wpR[j] = wbR[j] * invPR;   // normalized read weight; also w_prev for t+1
        wpW[j] = wbW[j] * invPW;
      }
      ((float4*)rwl)[tid] = make_float4(wpR[0], wpR[1], wpR[2], wpR[3]);
      ((float4*)wwl)[tid] = make_float4(wpW[0], wpW[1], wpW[2], wpW[3]);
      if (lane == 63) { pRj3[wv] = wpR[3]; pWj3[wv] = wpW[3]; }
      if (lane == 0)  { pRj0[wv] = wpR[0]; pWj0[wv] = wpW[0]; }
    }
    __syncthreads();

    // ---------------- sweep B: read vector + memory update (wave per 4 w-rows) ----------------
    {
      const float4* rwl4 = (const float4*)rwl;
      const float4* wwl4 = (const float4*)wwl;
#pragma unroll
      for (int w2 = 0; w2 < 4; ++w2) {
        const int w = wv * 4 + w2;
        const float e_w = elds[w], a_w = alds[w];
        float racc = 0.f;
#pragma unroll 4
        for (int k2 = 0; k2 < 16; ++k2) {
          const int li = k2 * 64 + lane;       // float4 index within row
          float4 v = mem4[w * 1024 + li];
          float4 r4 = rwl4[li];
          float4 w4 = wwl4[li];
          racc += r4.x * v.x + r4.y * v.y + r4.z * v.z + r4.w * v.w;  // old mem
          v.x = fmaf(w4.x, a_w, fmaf(v.x, -(w4.x * e_w), v.x));
          v.y = fmaf(w4.y, a_w, fmaf(v.y, -(w4.y * e_w), v.y));
          v.z = fmaf(w4.z, a_w, fmaf(v.z, -(w4.z * e_w), v.z));
          v.w = fmaf(w4.w, a_w, fmaf(v.w, -(w4.w * e_w), v.w));
          mem4[w * 1024 + li] = v;
        }
        racc = waveSum(racc);
        if (lane == 0) rsum[w] = racc;         // already normalized (rw normalized)
      }
    }
    __syncthreads();
  }
}

extern "C" void kernel_launch(void* const* d_in, const int* in_sizes, int n_in,
                              void* d_out, int out_size, void* d_ws, size_t ws_size,
                              hipStream_t stream) {
  const float* inp = (const float*)d_in[0];
  const float* Wc  = (const float*)d_in[1];
  const float* bcv = (const float*)d_in[2];
  float* dout = (float*)d_out;
  float* memG = (float*)d_ws;   // 16 * 64 * 4096 * 4 B = 16 MB

  ntm_kernel<<<dim3(BATCH), dim3(NTHR), 0, stream>>>(inp, Wc, bcv, dout, memG);
}

// Round 5
// 753.845 us; speedup vs baseline: 10.5318x; 1.9804x over previous
//
#include <hip/hip_runtime.h>

#define T_STEPS 32
#define BATCH   16
#define NBPB    8                    // blocks per batch
#define NBLK    (BATCH * NBPB)       // 128
#define NTHR    1024
#define LSL     512                  // l-slots per block (L=4096/8)
#define MSTR    65                   // LDS stride: bank (l+w)%32 -> 2-way (free)
#define NIN     192
#define CO      332

// comm workspace layout (floats); all zeroed via hipMemsetAsync each launch
#define OFF_CTR   0                                        // [16][32] uints
#define OFF_SSUM  512                                      // [b][t][4]  S_R,S_W,P_R,P_W
#define OFF_RSUM  (OFF_SSUM + BATCH * T_STEPS * 4)         // [b][t][64] read-vector partials
#define OFF_HE    (OFF_RSUM + BATCH * T_STEPS * 64)        // [b][t][g][4] er halos  L_R/R_R/L_W/R_W
#define OFF_HP    (OFF_HE + BATCH * T_STEPS * NBPB * 4)    // [b][t0..32][g][4] wp halos
#define COMM_FLOATS (OFF_HP + BATCH * (T_STEPS + 1) * NBPB * 4)

__device__ __forceinline__ float waveSum(float v) {
#pragma unroll
  for (int off = 32; off > 0; off >>= 1) v += __shfl_xor(v, off, 64);
  return v;
}
__device__ __forceinline__ float sigmoidf(float x) { return 1.f / (1.f + __expf(-x)); }
__device__ __forceinline__ float softplusf(float x) { return x > 15.f ? x : log1pf(__expf(x)); }
__device__ __forceinline__ float aload(const float* p) {
  return __hip_atomic_load(p, __ATOMIC_RELAXED, __HIP_MEMORY_SCOPE_AGENT);
}
__device__ __forceinline__ void astore(float* p, float v) {
  __hip_atomic_store(p, v, __ATOMIC_RELAXED, __HIP_MEMORY_SCOPE_AGENT);
}

// 8-block (per-batch) barrier. __syncthreads drains every thread's outstanding
// vmem/atomics (vmcnt(0) before s_barrier), so published atomics are globally
// visible before thread 0 bumps the counter. No __threadfence -> no L2 flush.
__device__ __forceinline__ void gbar(unsigned* c, unsigned expected) {
  __syncthreads();
  if (threadIdx.x == 0) {
    atomicAdd(c, 1u);
    while (__hip_atomic_load(c, __ATOMIC_RELAXED, __HIP_MEMORY_SCOPE_AGENT) < expected)
      __builtin_amdgcn_s_sleep(2);
  }
  __syncthreads();
}

__global__ void __launch_bounds__(NTHR, 1) ntm_kernel(
    const float* __restrict__ inp, const float* __restrict__ Wc,
    const float* __restrict__ bcv, float* __restrict__ dout,
    float* __restrict__ comm)
{
  const int b   = blockIdx.x >> 3;   // batch
  const int g   = blockIdx.x & 7;    // l-chunk within batch
  const int tid = threadIdx.x;
  const int wv  = tid >> 6;
  const int lane = tid & 63;

  __shared__ float mem[LSL * MSTR];               // 133 KB, block-private
  __shared__ float wpR[LSL], wpW[LSL];            // normalized weights (prev/cur)
  __shared__ float wbR[LSL], wbW[LSL];            // sharpened, unnormalized
  __shared__ float erR[LSL], erW[LSL];            // softmax numerators
  __shared__ float xin[NIN], kr[64], kw[64], psc[12], elds[64], alds[64];
  __shared__ float outb[2][64], scrA[8], scrB[8], red[8], rpart[64], edge[8];

  unsigned* ctr = (unsigned*)comm + b * 32;

  // ---------------- prologue ----------------
  for (int i = tid; i < LSL * MSTR; i += NTHR) mem[i] = 0.f;
  if (tid < LSL) { wpR[tid] = 0.f; wpW[tid] = 0.f; }
  if (g == 0 && tid == 0) { wpR[0] = 1.f; wpW[0] = 1.f; }  // w0 one-hot at l=0
  if (tid < 64) { outb[0][tid] = 0.f; outb[1][tid] = 0.f; }
  {
    float* hp0 = comm + OFF_HP + ((size_t)(b * (T_STEPS + 1) + 0) * NBPB + g) * 4;
    if (tid == 0)       { float v = (g == 0) ? 1.f : 0.f; astore(hp0 + 0, v); astore(hp0 + 2, v); }
    if (tid == LSL - 1) { astore(hp0 + 1, 0.f); astore(hp0 + 3, 0.f); }
  }
  unsigned expct = NBPB;
  gbar(ctr, expct);

  for (int t = 0; t < T_STEPS; ++t) {
    float* sS  = comm + OFF_SSUM + (size_t)(b * T_STEPS + t) * 4;
    float* rS  = comm + OFF_RSUM + (size_t)(b * T_STEPS + t) * 64;
    float* hE  = comm + OFF_HE + ((size_t)(b * T_STEPS + t) * NBPB + g) * 4;
    float* hPn = comm + OFF_HP + ((size_t)(b * (T_STEPS + 1) + t + 1) * NBPB + g) * 4;

    // ---------------- phase 0: stage input + controller GEMM ----------------
    if (tid < 64)       xin[tid] = inp[((size_t)t * BATCH + b) * 64 + tid];
    else if (tid < 128) xin[tid] = outb[(t + 1) & 1][tid - 64];
    else if (tid < 192) xin[tid] = (t == 0) ? 0.f
                        : aload(comm + OFF_RSUM + (size_t)(b * T_STEPS + t - 1) * 64 + (tid - 128));
    __syncthreads();

    if (tid < 2 * CO) {
      const int col = tid >> 1, h = tid & 1;
      float acc = h ? 0.f : bcv[col];
      const float* wcp = Wc + col + (size_t)(96 * h) * CO;
#pragma unroll 8
      for (int i = 0; i < 96; ++i) acc = fmaf(xin[96 * h + i], wcp[(size_t)i * CO], acc);
      acc += __shfl_xor(acc, 1, 64);
      if (h == 0) {
        if (col < 64) {
          outb[t & 1][col] = acc;
          if (g == 0) dout[((size_t)t * BATCH + b) * 64 + col] = acc;
        }
        else if (col < 128) kr[col - 64] = acc;
        else if (col < 134) psc[col - 128] = acc;        // beta_r,g_r,ga_r,s_r0..2
        else if (col < 198) kw[col - 134] = acc;
        else if (col < 204) psc[6 + (col - 198)] = acc;  // beta_w,g_w,ga_w,s_w0..2
        else if (col < 268) elds[col - 204] = sigmoidf(acc);
        else                alds[col - 268] = acc;
      }
    }
    __syncthreads();
    if (wv == 0)      { float v = kr[lane]; float s = waveSum(v * v); if (!lane) red[4] = 1.f / sqrtf(s + 1e-14f); }
    else if (wv == 1) { float v = kw[lane]; float s = waveSum(v * v); if (!lane) red[5] = 1.f / sqrtf(s + 1e-14f); }
    __syncthreads();

    // ---------------- phase 1: content addressing (thread per l, LDS) ----------------
    {
      float sRl = 0.f, sWl = 0.f;
      if (tid < LSL) {
        const float invnkR = red[4], betaR = softplusf(psc[0]);
        const float invnkW = red[5], betaW = softplusf(psc[6]);
        float ss = 0.f, dr = 0.f, dw = 0.f;
        const int base = tid * MSTR;
#pragma unroll 8
        for (int w = 0; w < 64; ++w) {
          float v = mem[base + w];
          ss = fmaf(v, v, ss); dr = fmaf(v, kr[w], dr); dw = fmaf(v, kw[w], dw);
        }
        float rinv = rsqrtf(ss + 1e-14f);
        float eRv = __expf(betaR * (dr * rinv * invnkR - 1.f));   // stable: K<=1
        float eWv = __expf(betaW * (dw * rinv * invnkW - 1.f));
        erR[tid] = eRv; erW[tid] = eWv;
        if (tid == 0)       { astore(hE + 0, eRv); astore(hE + 2, eWv); }
        if (tid == LSL - 1) { astore(hE + 1, eRv); astore(hE + 3, eWv); }
        sRl = eRv; sWl = eWv;
      }
      sRl = waveSum(sRl); sWl = waveSum(sWl);
      if (!lane && wv < 8) { scrA[wv] = sRl; scrB[wv] = sWl; }
      __syncthreads();
      if (tid == 0) {
        float a = 0.f, bb = 0.f;
        for (int j = 0; j < 8; ++j) { a += scrA[j]; bb += scrB[j]; }
        atomicAdd(sS + 0, a); atomicAdd(sS + 1, bb);
      }
    }
    expct += NBPB; gbar(ctr, expct);

    // ---------------- phase 2: gate + shift + sharpen ----------------
    {
      const int gm = (g + NBPB - 1) & 7, gp = (g + 1) & 7;
      const float* hEm = comm + OFF_HE + ((size_t)(b * T_STEPS + t) * NBPB + gm) * 4;
      const float* hEp = comm + OFF_HE + ((size_t)(b * T_STEPS + t) * NBPB + gp) * 4;
      const float* hPm = comm + OFF_HP + ((size_t)(b * (T_STEPS + 1) + t) * NBPB + gm) * 4;
      const float* hPp = comm + OFF_HP + ((size_t)(b * (T_STEPS + 1) + t) * NBPB + gp) * 4;
      if (tid == 0) { red[0] = 1.f / aload(sS + 0); red[1] = 1.f / aload(sS + 1); }
      if (tid == 1) { edge[0] = aload(hEm + 1); edge[1] = aload(hEm + 3);
                      edge[2] = aload(hPm + 1); edge[3] = aload(hPm + 3); }
      if (tid == 2) { edge[4] = aload(hEp + 0); edge[5] = aload(hEp + 2);
                      edge[6] = aload(hPp + 0); edge[7] = aload(hPp + 2); }
      __syncthreads();

      float pRl = 0.f, pWl = 0.f;
      if (tid < LSL) {
        const float invSR = red[0], invSW = red[1];
        float gR = sigmoidf(psc[1]), gaR = softplusf(psc[2]) + 1.f;
        float x0 = psc[3], x1 = psc[4], x2 = psc[5];
        float mx = fmaxf(x0, fmaxf(x1, x2));
        float e0 = __expf(x0 - mx), e1 = __expf(x1 - mx), e2 = __expf(x2 - mx);
        float es = 1.f / (e0 + e1 + e2);
        float sr0 = e0 * es, sr1 = e1 * es, sr2 = e2 * es;
        float gW = sigmoidf(psc[7]), gaW = softplusf(psc[8]) + 1.f;
        float y0 = psc[9], y1 = psc[10], y2 = psc[11];
        float my = fmaxf(y0, fmaxf(y1, y2));
        float f0 = __expf(y0 - my), f1 = __expf(y1 - my), f2 = __expf(y2 - my);
        float fs = 1.f / (f0 + f1 + f2);
        float sw0 = f0 * fs, sw1 = f1 * fs, sw2 = f2 * fs;
        const float aR = gR * invSR, bR = 1.f - gR;
        const float aW = gW * invSW, bW = 1.f - gW;

        float erm = tid ? erR[tid - 1] : edge[0];
        float ewm = tid ? erW[tid - 1] : edge[1];
        float prm = tid ? wpR[tid - 1] : edge[2];
        float pwm = tid ? wpW[tid - 1] : edge[3];
        float erp = (tid < LSL - 1) ? erR[tid + 1] : edge[4];
        float ewp = (tid < LSL - 1) ? erW[tid + 1] : edge[5];
        float prp = (tid < LSL - 1) ? wpR[tid + 1] : edge[6];
        float pwp = (tid < LSL - 1) ? wpW[tid + 1] : edge[7];

        float wgm = aR * erm + bR * prm;
        float wg0 = aR * erR[tid] + bR * wpR[tid];
        float wgp = aR * erp + bR * prp;
        float wR = __powf(sr0 * wgm + sr1 * wg0 + sr2 * wgp, gaR);
        float vgm = aW * ewm + bW * pwm;
        float vg0 = aW * erW[tid] + bW * wpW[tid];
        float vgp = aW * ewp + bW * pwp;
        float wW = __powf(sw0 * vgm + sw1 * vg0 + sw2 * vgp, gaW);
        wbR[tid] = wR; wbW[tid] = wW;
        pRl = wR; pWl = wW;
      }
      pRl = waveSum(pRl); pWl = waveSum(pWl);
      if (!lane && wv < 8) { scrA[wv] = pRl; scrB[wv] = pWl; }
      __syncthreads();
      if (tid == 0) {
        float a = 0.f, bb = 0.f;
        for (int j = 0; j < 8; ++j) { a += scrA[j]; bb += scrB[j]; }
        atomicAdd(sS + 2, a); atomicAdd(sS + 3, bb);
      }
    }
    expct += NBPB; gbar(ctr, expct);

    // ---------------- phase 3: normalize + read vector + memory update ----------------
    {
      if (tid == 0) { red[2] = 1.f / aload(sS + 2); red[3] = 1.f / aload(sS + 3); }
      __syncthreads();
      if (tid < LSL) {
        float nR = wbR[tid] * red[2];
        float nW = wbW[tid] * red[3];
        wpR[tid] = nR; wpW[tid] = nW;       // read/write weights; w_prev for t+1
        if (tid == 0)       { astore(hPn + 0, nR); astore(hPn + 2, nW); }
        if (tid == LSL - 1) { astore(hPn + 1, nR); astore(hPn + 3, nW); }
      }
      __syncthreads();

      // wave per 4 w-rows; per-lane l-set reused across rows
      float rwv[8], wwv[8];
#pragma unroll
      for (int k = 0; k < 8; ++k) { rwv[k] = wpR[lane + 64 * k]; wwv[k] = wpW[lane + 64 * k]; }
#pragma unroll
      for (int r2 = 0; r2 < 4; ++r2) {
        const int w = wv * 4 + r2;
        const float e_w = elds[w], a_w = alds[w];
        float racc = 0.f;
#pragma unroll
        for (int k = 0; k < 8; ++k) {
          const int idx = (lane + 64 * k) * MSTR + w;
          float v = mem[idx];
          racc = fmaf(v, rwv[k], racc);               // read from OLD memory
          float nv = fmaf(v, -(wwv[k] * e_w), v);     // v*(1 - ww*e)
          mem[idx] = fmaf(wwv[k], a_w, nv);           // + ww*a
        }
        racc = waveSum(racc);
        if (!lane) rpart[w] = racc;
      }
      __syncthreads();
      if (tid < 64) atomicAdd(rS + tid, rpart[tid]);
    }
    expct += NBPB; gbar(ctr, expct);
  }
}

extern "C" void kernel_launch(void* const* d_in, const int* in_sizes, int n_in,
                              void* d_out, int out_size, void* d_ws, size_t ws_size,
                              hipStream_t stream) {
  const float* inp = (const float*)d_in[0];
  const float* Wc  = (const float*)d_in[1];
  const float* bcv = (const float*)d_in[2];
  float* dout = (float*)d_out;
  float* comm = (float*)d_ws;

  // zero barrier counters + accumulation slots (capture-legal stream op)
  hipMemsetAsync(comm, 0, (size_t)COMM_FLOATS * sizeof(float), stream);

  void* args[] = { (void*)&inp, (void*)&Wc, (void*)&bcv, (void*)&dout, (void*)&comm };
  hipLaunchCooperativeKernel((void*)ntm_kernel, dim3(NBLK), dim3(NTHR),
                             args, 0, stream);
}

// Round 6
// 710.840 us; speedup vs baseline: 11.1689x; 1.0605x over previous
//
#include <hip/hip_runtime.h>

#define T_STEPS 32
#define BATCH   16
#define NBPB    8                    // blocks per batch
#define NBLK    (BATCH * NBPB)       // 128
#define NTHR    1024
#define LSL     512                  // l-slots per block
#define MSTR    65                   // LDS stride: bank (l+w)%32 -> 2-way (free)
#define NIN     192
#define CO      332

// comm workspace (floats), zeroed by hipMemsetAsync each launch
#define OFF_CTR   0                                        // [16][32] uints (barrier ctrs)
#define OFF_SSUM  512                                      // [b][t][4]  S_R,S_W,P_R,P_W
#define OFF_RSUM  (OFF_SSUM + BATCH * T_STEPS * 4)         // [b][t][64] unnormalized read partials
#define OFF_HE    (OFF_RSUM + BATCH * T_STEPS * 64)        // [b][t][g][4] er halos
#define OFF_HP    (OFF_HE + BATCH * T_STEPS * NBPB * 4)    // [b][t=0..32][g][4] normalized wp halos
#define COMM_FLOATS (OFF_HP + BATCH * (T_STEPS + 1) * NBPB * 4)

__device__ __forceinline__ float waveSum(float v) {
#pragma unroll
  for (int off = 32; off > 0; off >>= 1) v += __shfl_xor(v, off, 64);
  return v;
}
__device__ __forceinline__ float sigmoidf(float x) { return 1.f / (1.f + __expf(-x)); }
__device__ __forceinline__ float softplusf(float x) { return x > 15.f ? x : log1pf(__expf(x)); }
__device__ __forceinline__ float aload(const float* p) {
  return __hip_atomic_load(p, __ATOMIC_RELAXED, __HIP_MEMORY_SCOPE_AGENT);
}
__device__ __forceinline__ void astore(float* p, float v) {
  __hip_atomic_store(p, v, __ATOMIC_RELAXED, __HIP_MEMORY_SCOPE_AGENT);
}

// 8-block per-batch barrier. __syncthreads drains each thread's outstanding
// vmem/atomics (vmcnt(0) before s_barrier), so all published data is visible
// before thread 0 bumps the counter.
__device__ __forceinline__ void gbar(unsigned* c, unsigned expected) {
  __syncthreads();
  if (threadIdx.x == 0) {
    atomicAdd(c, 1u);
    while (__hip_atomic_load(c, __ATOMIC_RELAXED, __HIP_MEMORY_SCOPE_AGENT) < expected)
      __builtin_amdgcn_s_sleep(1);
  }
  __syncthreads();
}

__global__ void __launch_bounds__(NTHR, 1) ntm_kernel(
    const float* __restrict__ inp, const float* __restrict__ Wc,
    const float* __restrict__ bcv, float* __restrict__ dout,
    float* __restrict__ comm)
{
  // XCD co-location: blockIdx = g*16 + b  ->  blockIdx%8 == b%8, so all 8
  // blocks of a batch land on one XCD (round-robin dispatch) -> local-L2 atomics.
  const int b   = blockIdx.x & 15;
  const int g   = blockIdx.x >> 4;
  const int tid = threadIdx.x;
  const int wv  = tid >> 6;
  const int lane = tid & 63;

  __shared__ float mem[LSL * MSTR];               // 133 KB, block-private
  __shared__ float wpR[LSL], wpW[LSL];            // normalized prev weights
  __shared__ float wbR[LSL], wbW[LSL];            // sharpened, unnormalized
  __shared__ float erR[LSL], erW[LSL];            // softmax numerators
  __shared__ float xin[NIN], kr[64], kw[64], psc[12], elds[64], alds[64];
  __shared__ float outb[2][64], scrA[16], scrB[16], red[8], rpart[64];
  __shared__ float edge[8], coef[12];

  unsigned* ctr = (unsigned*)comm + b * 32;

  // ---------------- prologue ----------------
  for (int i = tid; i < LSL * MSTR; i += NTHR) mem[i] = 0.f;
  if (tid < LSL) { wpR[tid] = 0.f; wpW[tid] = 0.f; }
  if (g == 0 && tid == 0) { wpR[0] = 1.f; wpW[0] = 1.f; }  // w0 one-hot at l=0
  if (tid < 64) { outb[0][tid] = 0.f; outb[1][tid] = 0.f; }
  {
    float* hp0 = comm + OFF_HP + ((size_t)(b * (T_STEPS + 1) + 0) * NBPB + g) * 4;
    if (tid == 0)       { float v = (g == 0) ? 1.f : 0.f; astore(hp0 + 0, v); astore(hp0 + 2, v); }
    if (tid == LSL - 1) { astore(hp0 + 1, 0.f); astore(hp0 + 3, 0.f); }
  }
  unsigned expct = NBPB;
  gbar(ctr, expct);

  for (int t = 0; t < T_STEPS; ++t) {
    float* sS  = comm + OFF_SSUM + (size_t)(b * T_STEPS + t) * 4;
    float* rS  = comm + OFF_RSUM + (size_t)(b * T_STEPS + t) * 64;
    float* hE  = comm + OFF_HE + ((size_t)(b * T_STEPS + t) * NBPB + g) * 4;
    float* hPn = comm + OFF_HP + ((size_t)(b * (T_STEPS + 1) + t + 1) * NBPB + g) * 4;

    // ---------------- phase 0: stage input + controller GEMM ----------------
    if (tid < 64)       xin[tid] = inp[((size_t)t * BATCH + b) * 64 + tid];
    else if (tid < 128) xin[tid] = outb[(t + 1) & 1][tid - 64];
    else if (tid < 192) {
      if (t == 0) xin[tid] = 0.f;
      else {
        const float* sP = comm + OFF_SSUM + (size_t)(b * T_STEPS + t - 1) * 4;
        const float* rP = comm + OFF_RSUM + (size_t)(b * T_STEPS + t - 1) * 64;
        xin[tid] = aload(rP + (tid - 128)) / aload(sP + 2);   // r = r~ / P_R
      }
    }
    __syncthreads();

    if (tid < 2 * CO) {
      const int col = tid >> 1, h = tid & 1;
      float acc = h ? 0.f : bcv[col];
      const float* wcp = Wc + col + (size_t)(96 * h) * CO;
#pragma unroll 8
      for (int i = 0; i < 96; ++i) acc = fmaf(xin[96 * h + i], wcp[(size_t)i * CO], acc);
      acc += __shfl_xor(acc, 1, 64);
      if (h == 0) {
        if (col < 64) {
          outb[t & 1][col] = acc;
          if (g == 0) dout[((size_t)t * BATCH + b) * 64 + col] = acc;
        }
        else if (col < 128) kr[col - 64] = acc;
        else if (col < 134) psc[col - 128] = acc;        // beta_r,g_r,ga_r,s_r0..2
        else if (col < 198) kw[col - 134] = acc;
        else if (col < 204) psc[6 + (col - 198)] = acc;  // beta_w,g_w,ga_w,s_w0..2
        else if (col < 268) elds[col - 204] = sigmoidf(acc);
        else                alds[col - 268] = acc;
      }
    }
    __syncthreads();
    if (wv == 0)      { float v = kr[lane]; float s = waveSum(v * v); if (!lane) red[4] = 1.f / sqrtf(s + 1e-14f); }
    else if (wv == 1) { float v = kw[lane]; float s = waveSum(v * v); if (!lane) red[5] = 1.f / sqrtf(s + 1e-14f); }
    else if (wv == 2 && !lane) { red[6] = softplusf(psc[0]); red[7] = softplusf(psc[6]); }
    __syncthreads();

    // ---------------- phase 1: content addressing (2 threads per l) ----------------
    {
      const float invnkR = red[4], invnkW = red[5];
      const float betaR = red[6], betaW = red[7];
      const int l = tid >> 1, h = tid & 1;
      const int base = l * MSTR + 32 * h;
      const float* krh = kr + 32 * h;
      const float* kwh = kw + 32 * h;
      float ss = 0.f, dr = 0.f, dw = 0.f;
#pragma unroll 8
      for (int i = 0; i < 32; ++i) {
        float v = mem[base + i];
        ss = fmaf(v, v, ss); dr = fmaf(v, krh[i], dr); dw = fmaf(v, kwh[i], dw);
      }
      ss += __shfl_xor(ss, 1, 64);
      dr += __shfl_xor(dr, 1, 64);
      dw += __shfl_xor(dw, 1, 64);
      float rinv = rsqrtf(ss + 1e-14f);
      float eRv = __expf(betaR * (dr * rinv * invnkR - 1.f));   // stable: K<=1
      float eWv = __expf(betaW * (dw * rinv * invnkW - 1.f));
      if (h == 0) {
        erR[l] = eRv; erW[l] = eWv;
        if (l == 0)       { astore(hE + 0, eRv); astore(hE + 2, eWv); }
        if (l == LSL - 1) { astore(hE + 1, eRv); astore(hE + 3, eWv); }
      }
      float sRl = h ? 0.f : eRv, sWl = h ? 0.f : eWv;
      sRl = waveSum(sRl); sWl = waveSum(sWl);
      if (!lane) { scrA[wv] = sRl; scrB[wv] = sWl; }
      __syncthreads();
      if (tid == 0) {
        float a = 0.f, bb = 0.f;
        for (int j = 0; j < 16; ++j) { a += scrA[j]; bb += scrB[j]; }
        atomicAdd(sS + 0, a); atomicAdd(sS + 1, bb);
      }
    }
    expct += NBPB; gbar(ctr, expct);   // barrier A

    // ---------------- phase 2: sharpen + unnormalized read partials ----------------
    {
      const int gm = (g + NBPB - 1) & 7, gp = (g + 1) & 7;
      if (tid == 0) {
        float invSR = 1.f / aload(sS + 0), invSW = 1.f / aload(sS + 1);
        float gR = sigmoidf(psc[1]); coef[0] = gR * invSR; coef[1] = 1.f - gR;
        coef[2] = softplusf(psc[2]) + 1.f;
        float x0 = psc[3], x1 = psc[4], x2 = psc[5];
        float mx = fmaxf(x0, fmaxf(x1, x2));
        float e0 = __expf(x0 - mx), e1 = __expf(x1 - mx), e2 = __expf(x2 - mx);
        float es = 1.f / (e0 + e1 + e2);
        coef[3] = e0 * es; coef[4] = e1 * es; coef[5] = e2 * es;
        float gW = sigmoidf(psc[7]); coef[6] = gW * invSW; coef[7] = 1.f - gW;
        coef[8] = softplusf(psc[8]) + 1.f;
        float y0 = psc[9], y1 = psc[10], y2 = psc[11];
        float my = fmaxf(y0, fmaxf(y1, y2));
        float f0 = __expf(y0 - my), f1 = __expf(y1 - my), f2 = __expf(y2 - my);
        float fs = 1.f / (f0 + f1 + f2);
        coef[9] = f0 * fs; coef[10] = f1 * fs; coef[11] = f2 * fs;
      }
      if (tid == 1) {
        const float* hEm = comm + OFF_HE + ((size_t)(b * T_STEPS + t) * NBPB + gm) * 4;
        const float* hPm = comm + OFF_HP + ((size_t)(b * (T_STEPS + 1) + t) * NBPB + gm) * 4;
        edge[0] = aload(hEm + 1); edge[1] = aload(hEm + 3);
        edge[2] = aload(hPm + 1); edge[3] = aload(hPm + 3);
      }
      if (tid == 2) {
        const float* hEp = comm + OFF_HE + ((size_t)(b * T_STEPS + t) * NBPB + gp) * 4;
        const float* hPp = comm + OFF_HP + ((size_t)(b * (T_STEPS + 1) + t) * NBPB + gp) * 4;
        edge[4] = aload(hEp + 0); edge[5] = aload(hEp + 2);
        edge[6] = aload(hPp + 0); edge[7] = aload(hPp + 2);
      }
      __syncthreads();

      float pRl = 0.f, pWl = 0.f;
      if (tid < LSL) {
        const float aR = coef[0], bR = coef[1], gaR = coef[2];
        const float sr0 = coef[3], sr1 = coef[4], sr2 = coef[5];
        const float aW = coef[6], bW = coef[7], gaW = coef[8];
        const float sw0 = coef[9], sw1 = coef[10], sw2 = coef[11];

        float erm = tid ? erR[tid - 1] : edge[0];
        float ewm = tid ? erW[tid - 1] : edge[1];
        float prm = tid ? wpR[tid - 1] : edge[2];
        float pwm = tid ? wpW[tid - 1] : edge[3];
        float erp = (tid < LSL - 1) ? erR[tid + 1] : edge[4];
        float ewp = (tid < LSL - 1) ? erW[tid + 1] : edge[5];
        float prp = (tid < LSL - 1) ? wpR[tid + 1] : edge[6];
        float pwp = (tid < LSL - 1) ? wpW[tid + 1] : edge[7];

        float wgm = aR * erm + bR * prm;
        float wg0 = aR * erR[tid] + bR * wpR[tid];
        float wgp = aR * erp + bR * prp;
        float wR = __powf(sr0 * wgm + sr1 * wg0 + sr2 * wgp, gaR);
        float vgm = aW * ewm + bW * pwm;
        float vg0 = aW * erW[tid] + bW * wpW[tid];
        float vgp = aW * ewp + bW * pwp;
        float wW = __powf(sw0 * vgm + sw1 * vg0 + sw2 * vgp, gaW);
        wbR[tid] = wR; wbW[tid] = wW;
        pRl = wR; pWl = wW;
      }
      pRl = waveSum(pRl); pWl = waveSum(pWl);
      if (!lane && wv < 8) { scrA[wv] = pRl; scrB[wv] = pWl; }
      __syncthreads();
      if (tid == 0) {
        float a = 0.f, bb = 0.f;
        for (int j = 0; j < 8; ++j) { a += scrA[j]; bb += scrB[j]; }
        atomicAdd(sS + 2, a); atomicAdd(sS + 3, bb);
      }
      // unnormalized read partials r~ = sum_l wbR[l] * mem[l][w] (OLD memory)
      float wbv[8];
#pragma unroll
      for (int k = 0; k < 8; ++k) wbv[k] = wbR[lane + 64 * k];
#pragma unroll
      for (int r2 = 0; r2 < 4; ++r2) {
        const int w = wv * 4 + r2;
        float racc = 0.f;
#pragma unroll
        for (int k = 0; k < 8; ++k)
          racc = fmaf(mem[(lane + 64 * k) * MSTR + w], wbv[k], racc);
        racc = waveSum(racc);
        if (!lane) rpart[w] = racc;
      }
      __syncthreads();
      if (tid < 64) atomicAdd(rS + tid, rpart[tid]);
    }
    expct += NBPB; gbar(ctr, expct);   // barrier B (last of the step)

    // ---------------- phase 3: normalize weights + memory update (local only) ----------------
    {
      if (tid == 0) { red[2] = 1.f / aload(sS + 2); red[3] = 1.f / aload(sS + 3); }
      __syncthreads();
      if (tid < LSL) {
        float nR = wbR[tid] * red[2];
        float nW = wbW[tid] * red[3];
        wpR[tid] = nR; wpW[tid] = nW;       // w_prev for t+1
        if (tid == 0)       { astore(hPn + 0, nR); astore(hPn + 2, nW); }
        if (tid == LSL - 1) { astore(hPn + 1, nR); astore(hPn + 3, nW); }
      }
      __syncthreads();
      float wwv[8];
#pragma unroll
      for (int k = 0; k < 8; ++k) wwv[k] = wpW[lane + 64 * k];
#pragma unroll
      for (int r2 = 0; r2 < 4; ++r2) {
        const int w = wv * 4 + r2;
        const float e_w = elds[w], a_w = alds[w];
#pragma unroll
        for (int k = 0; k < 8; ++k) {
          const int idx = (lane + 64 * k) * MSTR + w;
          float v = mem[idx];
          float nv = fmaf(v, -(wwv[k] * e_w), v);     // v*(1 - ww*e)
          mem[idx] = fmaf(wwv[k], a_w, nv);           // + ww*a
        }
      }
      // no barrier: next step's phase-0 __syncthreads orders LDS; halo stores
      // drain at barrier A of t+1 before any neighbor reads them.
    }
  }
}

extern "C" void kernel_launch(void* const* d_in, const int* in_sizes, int n_in,
                              void* d_out, int out_size, void* d_ws, size_t ws_size,
                              hipStream_t stream) {
  const float* inp = (const float*)d_in[0];
  const float* Wc  = (const float*)d_in[1];
  const float* bcv = (const float*)d_in[2];
  float* dout = (float*)d_out;
  float* comm = (float*)d_ws;

  hipMemsetAsync(comm, 0, (size_t)COMM_FLOATS * sizeof(float), stream);

  void* args[] = { (void*)&inp, (void*)&Wc, (void*)&bcv, (void*)&dout, (void*)&comm };
  hipLaunchCooperativeKernel((void*)ntm_kernel, dim3(NBLK), dim3(NTHR),
                             args, 0, stream);
}